// Round 1
// 850.537 us; speedup vs baseline: 1.2302x; 1.2302x over previous
//
#include <hip/hip_runtime.h>

#define D_MODEL 1024
#define NHEADS  16
#define DEPTH   64
#define BB      2
#define SS      2048
#define MROWS   (BB*SS)     // 4096
#define BHN     (BB*NHEADS) // 32

using f16 = _Float16;
using f16x4 = __attribute__((ext_vector_type(4))) _Float16;
using f16x8 = __attribute__((ext_vector_type(8))) _Float16;
using f32x4 = __attribute__((ext_vector_type(4))) float;

__device__ __forceinline__ void g2l16(const void* g, void* l) {
  __builtin_amdgcn_global_load_lds(
      (const __attribute__((address_space(1))) void*)g,
      (__attribute__((address_space(3))) void*)l, 16, 0, 0);
}

// ---- fp32 W[k][n] -> f16 Wt[n][k], 4 matrices via grid.z ----
__global__ __launch_bounds__(256) void wtrans(
    const float* __restrict__ w0, const float* __restrict__ w1,
    const float* __restrict__ w2, const float* __restrict__ w3,
    f16* __restrict__ wt) {
  const float* W = blockIdx.z == 0 ? w0 : blockIdx.z == 1 ? w1 : blockIdx.z == 2 ? w2 : w3;
  f16* Wt = wt + (size_t)blockIdx.z * D_MODEL * D_MODEL;
  __shared__ float tile[64][65];
  const int t = threadIdx.x;
  const int bx = blockIdx.x * 64, by = blockIdx.y * 64;
  const int c = t & 63, r0 = t >> 6;
#pragma unroll
  for (int i = 0; i < 16; ++i) {
    int r = r0 + i * 4;
    tile[r][c] = W[(size_t)(by + r) * D_MODEL + bx + c];
  }
  __syncthreads();
#pragma unroll
  for (int i = 0; i < 16; ++i) {
    int r = r0 + i * 4;
    Wt[(size_t)(bx + r) * D_MODEL + by + c] = (f16)tile[c][r];
  }
}

// ---- Q/K/V projection: A(fp32 4096x1024) @ Wt^T + bias -> heads f16 [b,h,s,64] ----
__global__ __launch_bounds__(256) void proj_gemm(
    const float* __restrict__ Q, const float* __restrict__ K, const float* __restrict__ V,
    const f16* __restrict__ Wt,
    const float* __restrict__ bq, const float* __restrict__ bk, const float* __restrict__ bv,
    f16* __restrict__ heads) {
  const int z = blockIdx.z;
  const float* A = z == 0 ? Q : z == 1 ? K : V;
  const f16* Bt = Wt + (size_t)z * D_MODEL * D_MODEL;
  const float* bias = z == 0 ? bq : z == 1 ? bk : bv;
  f16* dst = heads + (size_t)z * MROWS * D_MODEL;

  __shared__ f16 As[128 * 32];
  __shared__ f16 Bs[128 * 32];
  const int t = threadIdx.x, lane = t & 63, w = t >> 6;
  const int m0 = blockIdx.y * 128, n0 = blockIdx.x * 128;
  const int wr = (w >> 1) * 64, wc = (w & 1) * 64;
  f32x4 acc[4][4] = {};

  for (int k0 = 0; k0 < D_MODEL; k0 += 32) {
    __syncthreads();
#pragma unroll
    for (int i = 0; i < 4; ++i) {             // A: 128x32 fp32 -> f16 LDS
      int f = t + i * 256;
      int row = f >> 3, c4 = (f & 7) * 4;
      const float4 v4 = *(const float4*)(A + (size_t)(m0 + row) * D_MODEL + k0 + c4);
      f16* p = &As[row * 32 + c4];
      p[0] = (f16)v4.x; p[1] = (f16)v4.y; p[2] = (f16)v4.z; p[3] = (f16)v4.w;
    }
#pragma unroll
    for (int i = 0; i < 2; ++i) {             // B: 128x32 f16 via global_load_lds
      int seg = t + i * 256;
      int row = seg >> 2, c8 = (seg & 3) * 8;
      g2l16(Bt + (size_t)(n0 + row) * D_MODEL + k0 + c8, &Bs[seg * 8]);
    }
    __syncthreads();
    f16x8 af[4], bfr[4];
#pragma unroll
    for (int i = 0; i < 4; ++i)
      af[i] = *(const f16x8*)&As[(wr + i * 16 + (lane & 15)) * 32 + (lane >> 4) * 8];
#pragma unroll
    for (int j = 0; j < 4; ++j)
      bfr[j] = *(const f16x8*)&Bs[(wc + j * 16 + (lane & 15)) * 32 + (lane >> 4) * 8];
#pragma unroll
    for (int i = 0; i < 4; ++i)
#pragma unroll
      for (int j = 0; j < 4; ++j)
        acc[i][j] = __builtin_amdgcn_mfma_f32_16x16x32_f16(af[i], bfr[j], acc[i][j], 0, 0, 0);
  }
#pragma unroll
  for (int i = 0; i < 4; ++i)
#pragma unroll
    for (int j = 0; j < 4; ++j) {
      int n = n0 + wc + j * 16 + (lane & 15);
      float bn = bias[n];
      int h = n >> 6, d = n & 63;
#pragma unroll
      for (int r = 0; r < 4; ++r) {
        int m = m0 + wr + i * 16 + (lane >> 4) * 4 + r;
        int b = m >> 11, s = m & 2047;
        dst[((size_t)(b * NHEADS + h) * SS + s) * DEPTH + d] = (f16)(acc[i][j][r] + bn);
      }
    }
}

// ---- vh [bh][n][64] -> vt [bh][64][n]  (f16 transpose, 8 MB) ----
__global__ __launch_bounds__(256) void vtrans(
    const f16* __restrict__ vh, f16* __restrict__ vt) {
  const int bh = blockIdx.y;
  const int n0 = blockIdx.x * 128;
  const f16* src = vh + (size_t)bh * SS * DEPTH;
  f16* dst = vt + (size_t)bh * DEPTH * SS;
  __shared__ f16 tile[128][72];
  const int t = threadIdx.x;
#pragma unroll
  for (int iss = 0; iss < 4; ++iss) {
    int seg = t + iss * 256;            // 1024 chunks of 8 f16
    int n = seg >> 3, c = seg & 7;
    *(f16x8*)&tile[n][c * 8] = *(const f16x8*)(src + (size_t)(n0 + n) * DEPTH + c * 8);
  }
  __syncthreads();
#pragma unroll
  for (int iss = 0; iss < 4; ++iss) {
    int seg = t + iss * 256;            // 1024 out-chunks of 8 f16
    int d = seg >> 4, c = seg & 15;
    f16x8 v;
#pragma unroll
    for (int e = 0; e < 8; ++e) v[e] = tile[c * 8 + e][d];
    *(f16x8*)(dst + (size_t)d * SS + n0 + c * 8) = v;
  }
}

// ---- fused scores+softmax+PV.  Per block: 128 q-rows of one (b,h).
// Pass 1: S^T = mfma(K,Q) tiles -> online (rowmax, expsum).   (no S writes)
// Pass 2: recompute S^T bitwise-identically, p = exp(s-m)*inv, write attn fp32
//         ONCE, feed p from registers into PV via mfma 16x16x16 (layout match).
__global__ __launch_bounds__(256) void attn_fused(
    const f16* __restrict__ qh, const f16* __restrict__ kh,
    const f16* __restrict__ vt, const float* __restrict__ mask,
    float* __restrict__ attn, f16* __restrict__ outh) {
  const int bh = blockIdx.y, b = bh >> 4, h = bh & 15;
  const int m0 = blockIdx.x * 128;
  const f16* Kb = kh + (size_t)bh * SS * DEPTH;
  const f16* Vb = vt + (size_t)bh * DEPTH * SS;
  const float* mB = mask + (size_t)b * SS;
  float* Ab = attn + (size_t)bh * SS * SS;

  __shared__ f16 Ks[2][128 * 64];   // K tile, 16B-chunk c XOR (n&7) swizzle
  __shared__ f16 Vs[2][64 * 128];   // Vt tile, 16B-chunk c XOR ((d>>1)&7) swizzle

  const int t = threadIdx.x, lane = t & 63, w = t >> 6;
  const int l15 = lane & 15, g = lane >> 4;

  // Q fragments (B-operand of swapped QK): rows m = m0 + w*32 + j*16 + l15
  f16x8 bq[2][2];
  {
    const f16* Qb = qh + (size_t)bh * SS * DEPTH;
#pragma unroll
    for (int j = 0; j < 2; ++j)
#pragma unroll
      for (int kk = 0; kk < 2; ++kk)
        bq[j][kk] = *(const f16x8*)(Qb + (size_t)(m0 + w * 32 + j * 16 + l15) * DEPTH + kk * 32 + g * 8);
  }

  // --- staging (linear LDS dest, pre-swizzled global source: rule #21) ---
  auto stageK = [&](int buf, int ct) {
#pragma unroll
    for (int iss = 0; iss < 4; ++iss) {
      int seg = t + iss * 256;          // 0..1023, 16B each
      int n = seg >> 3, c = seg & 7;
      int csrc = c ^ (n & 7);
      g2l16(Kb + (size_t)(ct * 128 + n) * DEPTH + csrc * 8, &Ks[buf][seg * 8]);
    }
  };
  auto stageV = [&](int buf, int ct) {
#pragma unroll
    for (int iss = 0; iss < 4; ++iss) {
      int seg = t + iss * 256;          // 0..1023, 16B each
      int d = seg >> 4, c = seg & 15;
      int csrc = c ^ ((d >> 1) & 7);
      g2l16(Vb + (size_t)d * SS + ct * 128 + csrc * 8, &Vs[buf][seg * 8]);
    }
  };
  // S^T tile: D[n][m], n-frag i (8), m-frag j (2); identical in both passes.
  auto qkStep = [&](const f16* ks, f32x4 (&accS)[8][2]) {
#pragma unroll
    for (int kk = 0; kk < 2; ++kk) {
#pragma unroll
      for (int i = 0; i < 8; ++i) {
        int n = i * 16 + l15;
        int c = (g + 4 * kk) ^ (l15 & 7);           // n&7 == l15&7
        f16x8 ak = *(const f16x8*)&ks[n * 64 + c * 8];
#pragma unroll
        for (int j = 0; j < 2; ++j)
          accS[i][j] = __builtin_amdgcn_mfma_f32_16x16x32_f16(ak, bq[j][kk], accS[i][j], 0, 0, 0);
      }
    }
  };

  // ================= pass 1: online row stats =================
  float rm[2] = {-3.0e38f, -3.0e38f}, rs[2] = {0.0f, 0.0f};
  stageK(0, 0);
  __syncthreads();
  for (int ct = 0; ct < 16; ++ct) {
    const int cur = ct & 1;
    if (ct < 15) stageK(cur ^ 1, ct + 1);
    f32x4 accS[8][2] = {};
    qkStep(Ks[cur], accS);
#pragma unroll
    for (int i = 0; i < 8; ++i) {      // fold scale + mask in place
      const float4 m4 = *(const float4*)(mB + ct * 128 + i * 16 + g * 4);
      const float mv[4] = {m4.x * -1e9f, m4.y * -1e9f, m4.z * -1e9f, m4.w * -1e9f};
#pragma unroll
      for (int j = 0; j < 2; ++j)
#pragma unroll
        for (int r = 0; r < 4; ++r)
          accS[i][j][r] = accS[i][j][r] * 0.125f + mv[r];
    }
#pragma unroll
    for (int j = 0; j < 2; ++j) {
      float tm = -3.0e38f;
#pragma unroll
      for (int i = 0; i < 8; ++i)
        tm = fmaxf(tm, fmaxf(fmaxf(accS[i][j][0], accS[i][j][1]),
                             fmaxf(accS[i][j][2], accS[i][j][3])));
      tm = fmaxf(tm, __shfl_xor(tm, 16, 64));
      tm = fmaxf(tm, __shfl_xor(tm, 32, 64));
      const float mn = fmaxf(rm[j], tm);
      float ts = 0.0f;
#pragma unroll
      for (int i = 0; i < 8; ++i)
#pragma unroll
        for (int r = 0; r < 4; ++r)
          ts += __expf(accS[i][j][r] - mn);
      ts += __shfl_xor(ts, 16, 64);
      ts += __shfl_xor(ts, 32, 64);
      rs[j] = rs[j] * __expf(rm[j] - mn) + ts;
      rm[j] = mn;
    }
    __syncthreads();
  }

  // ================= pass 2: normalized attn write + PV =================
  const float invs[2] = {1.0f / rs[0], 1.0f / rs[1]};
  f32x4 accO[2][4] = {};
  stageK(0, 0); stageV(0, 0);
  __syncthreads();
  for (int ct = 0; ct < 16; ++ct) {
    const int cur = ct & 1;
    if (ct < 15) { stageK(cur ^ 1, ct + 1); stageV(cur ^ 1, ct + 1); }
    f32x4 accS[8][2] = {};
    qkStep(Ks[cur], accS);
    const f16* vs = Vs[cur];
#pragma unroll
    for (int i = 0; i < 8; ++i) {
      const float4 m4 = *(const float4*)(mB + ct * 128 + i * 16 + g * 4);
      const float mv[4] = {m4.x * -1e9f, m4.y * -1e9f, m4.z * -1e9f, m4.w * -1e9f};
      f16x4 bv[4];
#pragma unroll
      for (int df = 0; df < 4; ++df) {      // Vt[d][n-chunk], swizzled read
        const int d = df * 16 + l15;
        const int c16 = 2 * i + (g >> 1);
        const int sw = c16 ^ ((d >> 1) & 7);
        bv[df] = *(const f16x4*)&vs[d * 128 + sw * 8 + (g & 1) * 4];
      }
#pragma unroll
      for (int j = 0; j < 2; ++j) {
        float p[4];
#pragma unroll
        for (int r = 0; r < 4; ++r)
          p[r] = __expf(accS[i][j][r] * 0.125f + mv[r] - rm[j]) * invs[j];
        float4 st; st.x = p[0]; st.y = p[1]; st.z = p[2]; st.w = p[3];
        *(float4*)(Ab + (size_t)(m0 + w * 32 + j * 16 + l15) * SS + ct * 128 + i * 16 + g * 4) = st;
        f16x4 pa; pa[0] = (f16)p[0]; pa[1] = (f16)p[1]; pa[2] = (f16)p[2]; pa[3] = (f16)p[3];
#pragma unroll
        for (int df = 0; df < 4; ++df)       // S^T C-layout == 16x16x16 A-frag
          accO[j][df] = __builtin_amdgcn_mfma_f32_16x16x16f16(pa, bv[df], accO[j][df], 0, 0, 0);
      }
    }
    __syncthreads();
  }

  // epilogue: out[m][d], m = m0 + w*32 + j*16 + 4g + r, d = df*16 + l15
  f16* Ob = outh + (size_t)b * SS * D_MODEL + h * DEPTH;
#pragma unroll
  for (int j = 0; j < 2; ++j)
#pragma unroll
    for (int df = 0; df < 4; ++df) {
      const int d = df * 16 + l15;
#pragma unroll
      for (int r = 0; r < 4; ++r) {
        const int s = m0 + w * 32 + j * 16 + g * 4 + r;
        Ob[(size_t)s * D_MODEL + d] = (f16)accO[j][df][r];
      }
    }
}

// ---- out = outh(f16 4096x1024) @ Wo^T + bo -> fp32 d_out ----
__global__ __launch_bounds__(256) void final_gemm(
    const f16* __restrict__ A, const f16* __restrict__ Bt,
    const float* __restrict__ bias, float* __restrict__ out) {
  __shared__ f16 As[128 * 32];
  __shared__ f16 Bs[128 * 32];
  const int t = threadIdx.x, lane = t & 63, w = t >> 6;
  const int m0 = blockIdx.y * 128, n0 = blockIdx.x * 128;
  const int wr = (w >> 1) * 64, wc = (w & 1) * 64;
  f32x4 acc[4][4] = {};

  for (int k0 = 0; k0 < D_MODEL; k0 += 32) {
    __syncthreads();
#pragma unroll
    for (int i = 0; i < 2; ++i) {
      int seg = t + i * 256;
      int row = seg >> 2, c8 = (seg & 3) * 8;
      g2l16(A + (size_t)(m0 + row) * D_MODEL + k0 + c8, &As[seg * 8]);
      g2l16(Bt + (size_t)(n0 + row) * D_MODEL + k0 + c8, &Bs[seg * 8]);
    }
    __syncthreads();
    f16x8 af[4], bfr[4];
#pragma unroll
    for (int i = 0; i < 4; ++i)
      af[i] = *(const f16x8*)&As[(wr + i * 16 + (lane & 15)) * 32 + (lane >> 4) * 8];
#pragma unroll
    for (int j = 0; j < 4; ++j)
      bfr[j] = *(const f16x8*)&Bs[(wc + j * 16 + (lane & 15)) * 32 + (lane >> 4) * 8];
#pragma unroll
    for (int i = 0; i < 4; ++i)
#pragma unroll
      for (int j = 0; j < 4; ++j)
        acc[i][j] = __builtin_amdgcn_mfma_f32_16x16x32_f16(af[i], bfr[j], acc[i][j], 0, 0, 0);
  }
#pragma unroll
  for (int i = 0; i < 4; ++i)
#pragma unroll
    for (int j = 0; j < 4; ++j) {
      int n = n0 + wc + j * 16 + (lane & 15);
      float bn = bias[n];
#pragma unroll
      for (int r = 0; r < 4; ++r) {
        int m = m0 + wr + i * 16 + (lane >> 4) * 4 + r;
        out[(size_t)m * D_MODEL + n] = acc[i][j][r] + bn;
      }
    }
}

extern "C" void kernel_launch(void* const* d_in, const int* in_sizes, int n_in,
                              void* d_out, int out_size, void* d_ws, size_t ws_size,
                              hipStream_t stream) {
  const float* Q    = (const float*)d_in[0];
  const float* K    = (const float*)d_in[1];
  const float* V    = (const float*)d_in[2];
  const float* mask = (const float*)d_in[3];
  const float* Wq   = (const float*)d_in[4];
  const float* bq   = (const float*)d_in[5];
  const float* Wk   = (const float*)d_in[6];
  const float* bk   = (const float*)d_in[7];
  const float* Wv   = (const float*)d_in[8];
  const float* bv   = (const float*)d_in[9];
  const float* Wo   = (const float*)d_in[10];
  const float* bo   = (const float*)d_in[11];

  float* out0 = (float*)d_out;
  float* attn = out0 + (size_t)MROWS * D_MODEL;   // output 1 region

  char* ws = (char*)d_ws;
  f16* Wt    = (f16*)ws;                                   // 4 x 1M f16  =  8 MB
  f16* heads = (f16*)(ws + (size_t)8 * 1024 * 1024);       // 3 x 4M f16  = 24 MB
  f16* outh  = (f16*)(ws + (size_t)32 * 1024 * 1024);      // 4M f16      =  8 MB
  f16* vtr   = (f16*)(ws + (size_t)40 * 1024 * 1024);      // 4M f16      =  8 MB
  f16* qh = heads;
  f16* kh = heads + (size_t)MROWS * D_MODEL;
  f16* vh = heads + (size_t)2 * MROWS * D_MODEL;

  wtrans<<<dim3(16, 16, 4), 256, 0, stream>>>(Wq, Wk, Wv, Wo, Wt);
  proj_gemm<<<dim3(8, 32, 3), 256, 0, stream>>>(Q, K, V, Wt, bq, bk, bv, heads);
  vtrans<<<dim3(16, BHN), 256, 0, stream>>>(vh, vtr);
  attn_fused<<<dim3(16, BHN), 256, 0, stream>>>(qh, kh, vtr, mask, attn, outh);
  final_gemm<<<dim3(8, 32), 256, 0, stream>>>(outh, Wt + (size_t)3 * D_MODEL * D_MODEL, bo, out0);
}